// Round 1
// baseline (855.520 us; speedup 1.0000x reference)
//
#include <hip/hip_runtime.h>
#include <stdint.h>

// NodeModel: edge MLP (Lin 128->64 + BN(batch stats) + SiLU) -> scatter_mean -> node MLP.
// Recompute design + linear-split precompute:
//   P1 = x @ W1_top + b1  (bf16, [N,64])  -- computed once, gathered per edge
//   pass0: ea GEMM (K=64) + P1[row] -> column sum/sumsq
//   pass1: ea GEMM again + P1[row] -> norm+SiLU -> atomic scatter to sums/cnt
//   P2 = x @ W2_top + b2  (bf16, aliases P1 buffer)
//   pass2: agg GEMM (K=64) + P2 -> column sum/sumsq
//   pass3: agg GEMM again + P2 -> norm+SiLU -> f32 out
// Falls back to the previous (K=128 recompute) path if ws_size can't fit P.

#define EPS 1e-5f

using short8  = __attribute__((ext_vector_type(8))) short;
using floatx4 = __attribute__((ext_vector_type(4))) float;
using f32x4   = __attribute__((ext_vector_type(4))) float;

__device__ __forceinline__ ushort f2bf(float f) {
  uint32_t u = __builtin_bit_cast(uint32_t, f);
  u += 0x7fffu + ((u >> 16) & 1u);   // RNE
  return (ushort)(u >> 16);
}
__device__ __forceinline__ float bf2f(ushort u) {
  uint32_t x = ((uint32_t)u) << 16;
  return __builtin_bit_cast(float, x);
}
__device__ __forceinline__ float silu(float v) {
  return v / (1.0f + __expf(-v));
}
__device__ __forceinline__ void pack4(ushort* dst, f32x4 v) {
  uint2 p;
  p.x = (uint)f2bf(v.x) | ((uint)f2bf(v.y) << 16);
  p.y = (uint)f2bf(v.z) | ((uint)f2bf(v.w) << 16);
  *(uint2*)dst = p;
}

// P = x @ W_top + bias, stored bf16. W is [128,64] row-major; top = rows 0..63.
__global__ __launch_bounds__(256) void precompute_P(
    const float* __restrict__ x, const float* __restrict__ W,
    const float* __restrict__ bias, ushort* __restrict__ P,
    int nrows, int ntiles) {
  __shared__ __align__(16) ushort Xls[64 * 72];
  __shared__ __align__(16) ushort Wts[64 * 72];
  __shared__ float biasl[64];

  const int tid  = threadIdx.x;
  const int lane = tid & 63;
  const int wv   = tid >> 6;
  const int m    = lane & 15;
  const int quad = lane >> 4;

  for (int i = tid; i < 64 * 64; i += 256) {
    const int n = i >> 6, k = i & 63;
    Wts[n * 72 + k] = f2bf(W[k * 64 + n]);
  }
  if (tid < 64) biasl[tid] = bias[tid];

  for (int t = blockIdx.x; t < ntiles; t += gridDim.x) {
    __syncthreads();
    const int base = t * 64;
    for (int i = tid; i < 1024; i += 256) {   // 64 rows x 16 chunks
      const int e = i >> 4;
      const int c4 = (i & 15) << 2;
      const int grow = base + e;
      f32x4 v = {0.f, 0.f, 0.f, 0.f};
      if (grow < nrows) v = *(const f32x4*)(x + (size_t)grow * 64 + c4);
      pack4(&Xls[e * 72 + c4], v);
    }
    __syncthreads();

    floatx4 acc[4];
#pragma unroll
    for (int nt = 0; nt < 4; ++nt) acc[nt] = (floatx4){0.f, 0.f, 0.f, 0.f};
    const ushort* arow = &Xls[(wv * 16 + m) * 72];
#pragma unroll
    for (int kc = 0; kc < 2; ++kc) {
      const short8 af = *(const short8*)(arow + kc * 32 + quad * 8);
#pragma unroll
      for (int nt = 0; nt < 4; ++nt) {
        const short8 bfr = *(const short8*)(&Wts[(nt * 16 + m) * 72 + kc * 32 + quad * 8]);
        acc[nt] = __builtin_amdgcn_mfma_f32_16x16x32_bf16(af, bfr, acc[nt], 0, 0, 0);
      }
    }
    const int lr0 = wv * 16 + quad * 4;
#pragma unroll
    for (int nt = 0; nt < 4; ++nt) {
      const int c = nt * 16 + m;
      const float bb = biasl[c];
#pragma unroll
      for (int r = 0; r < 4; ++r) {
        const int grow = base + lr0 + r;
        if (grow < nrows) P[(size_t)grow * 64 + c] = f2bf(acc[nt][r] + bb);
      }
    }
  }
}

// MODE: 0 = edge stats, 1 = edge scatter, 2 = node stats, 3 = node out
// USEP: 1 = K=64 GEMM + P-fragment accumulator init; 0 = legacy K=128 recompute
template <int MODE, int USEP>
__global__ __launch_bounds__(256) void fused_gemm(
    const float* __restrict__ x, const float* __restrict__ ea,
    const float* __restrict__ sums_in, const float* __restrict__ cnt,
    const int* __restrict__ rowidx, const int* __restrict__ colidx,
    const float* __restrict__ W, const float* __restrict__ bias,
    const float* __restrict__ scsh, const ushort* __restrict__ Pbf,
    float* __restrict__ ssum, float* __restrict__ ssq,
    float* __restrict__ sums_out, float* __restrict__ cnt_out,
    float* __restrict__ out,
    float* __restrict__ zbuf, int zn,
    int nrows, int ntiles) {
  constexpr int KC = USEP ? 64 : 128;    // K columns staged per tile
  constexpr int KP = USEP ? 72 : 136;    // padded LDS leading dim (ushorts)
  constexpr int CH = KC / 4;             // float4 chunks per row
  __shared__ __align__(16) ushort Albs[64 * KP];
  __shared__ __align__(16) ushort Btl[64 * KP];
  __shared__ float wsum[4][64];
  __shared__ float wsq[4][64];
  __shared__ float biasl[64];
  __shared__ float scl[128];
  __shared__ int coltile[64];

  const int tid  = threadIdx.x;
  const int lane = tid & 63;
  const int wv   = tid >> 6;
  const int m    = lane & 15;
  const int quad = lane >> 4;

  // Fold workspace zeroing into pass0 (replaces serial 26MB memset).
  if (MODE == 0 && zbuf) {
    const int stride = gridDim.x * 256;
    const f32x4 z = {0.f, 0.f, 0.f, 0.f};
    for (int i = blockIdx.x * 256 + tid; i < (zn >> 2); i += stride)
      ((f32x4*)zbuf)[i] = z;
    if (blockIdx.x == 0 && tid < (zn & 3)) zbuf[(zn & ~3) + tid] = 0.f;
  }

  // Stage W^T (bf16): USEP uses bottom half (rows 64..127), legacy full K.
  for (int i = tid; i < 64 * KC; i += 256) {
    const int n = i / KC, k = i % KC;
    const int gk = USEP ? (64 + k) : k;
    Btl[n * KP + k] = f2bf(W[gk * 64 + n]);
  }
  if (!USEP) { if (tid < 64) biasl[tid] = bias[tid]; }
  if (MODE == 1 || MODE == 3) {
    if (tid < 128) scl[tid] = scsh[tid];
  }
  if (MODE == 0 || MODE == 2) {
    wsum[wv][lane] = 0.f;
    wsq[wv][lane]  = 0.f;
  }

  for (int t = blockIdx.x; t < ntiles; t += gridDim.x) {
    __syncthreads();  // prior tile's LDS reads done; also covers pre-loop staging
    const int base = t * 64;

    // Early prefetch of the P fragments for this wave's output rows (USEP).
    // Issued before staging so the random gather latency hides under it.
    float pv[4][4];
    if (USEP) {
#pragma unroll
      for (int r = 0; r < 4; ++r) {
        const int grow = base + wv * 16 + quad * 4 + r;
        float p0 = 0.f, p1 = 0.f, p2 = 0.f, p3 = 0.f;
        if (grow < nrows) {
          const int prow = (MODE <= 1) ? rowidx[grow] : grow;
          const ushort* pp = Pbf + (size_t)prow * 64 + m;
          p0 = bf2f(pp[0]);  p1 = bf2f(pp[16]);
          p2 = bf2f(pp[32]); p3 = bf2f(pp[48]);
        }
        pv[0][r] = p0; pv[1][r] = p1; pv[2][r] = p2; pv[3][r] = p3;
      }
    }

    // Stage A tile (bf16 into LDS).
    for (int i = tid; i < 64 * CH; i += 256) {
      const int e  = i / CH;
      const int c4 = (i % CH) << 2;
      const int grow = base + e;
      f32x4 v = {0.f, 0.f, 0.f, 0.f};
      if (grow < nrows) {
        if (USEP) {
          if (MODE <= 1) {
            v = __builtin_nontemporal_load((const f32x4*)(ea + (size_t)grow * 64 + c4));
            if (MODE == 1 && c4 == 0) coltile[e] = colidx[grow];
          } else {
            const float inv = 1.0f / fmaxf(cnt[grow], 1.0f);
            v = *(const f32x4*)(sums_in + (size_t)grow * 64 + c4);
            v *= inv;
          }
        } else {
          if (MODE <= 1) {
            if (c4 < 64) {
              const int r = rowidx[grow];
              v = *(const f32x4*)(x + (size_t)r * 64 + c4);
            } else {
              v = __builtin_nontemporal_load((const f32x4*)(ea + (size_t)grow * 64 + (c4 - 64)));
            }
            if (MODE == 1 && c4 == 0) coltile[e] = colidx[grow];
          } else {
            if (c4 < 64) {
              v = *(const f32x4*)(x + (size_t)grow * 64 + c4);
            } else {
              const float inv = 1.0f / fmaxf(cnt[grow], 1.0f);
              v = *(const f32x4*)(sums_in + (size_t)grow * 64 + (c4 - 64));
              v *= inv;
            }
          }
        }
      }
      pack4(&Albs[e * KP + c4], v);
    }
    __syncthreads();

    floatx4 acc[4];
#pragma unroll
    for (int nt = 0; nt < 4; ++nt) acc[nt] = (floatx4){0.f, 0.f, 0.f, 0.f};
    const ushort* arow = &Albs[(wv * 16 + m) * KP];
#pragma unroll
    for (int kc = 0; kc < KC / 32; ++kc) {
      const short8 af = *(const short8*)(arow + kc * 32 + quad * 8);
#pragma unroll
      for (int nt = 0; nt < 4; ++nt) {
        const short8 bfr = *(const short8*)(&Btl[(nt * 16 + m) * KP + kc * 32 + quad * 8]);
        acc[nt] = __builtin_amdgcn_mfma_f32_16x16x32_bf16(af, bfr, acc[nt], 0, 0, 0);
      }
    }

    // Epilogue. C/D layout: col = lane&15 (+nt*16), row = quad*4 + reg (m89-verified)
    const int lr0 = wv * 16 + quad * 4;
#pragma unroll
    for (int nt = 0; nt < 4; ++nt) {
      const int c = nt * 16 + m;
      const float bb = USEP ? 0.f : biasl[c];   // USEP: bias folded into P
      if (MODE == 0 || MODE == 2) {
        float s = 0.f, q = 0.f;
#pragma unroll
        for (int r = 0; r < 4; ++r) {
          const int grow = base + lr0 + r;
          if (grow < nrows) {
            const float v = acc[nt][r] + (USEP ? pv[nt][r] : bb);
            s += v;
            q += v * v;
          }
        }
        s += __shfl_xor(s, 16); s += __shfl_xor(s, 32);
        q += __shfl_xor(q, 16); q += __shfl_xor(q, 32);
        if (quad == 0) { wsum[wv][c] += s; wsq[wv][c] += q; }
      } else {
        const float sc = scl[c];
        const float sh = scl[64 + c];
#pragma unroll
        for (int r = 0; r < 4; ++r) {
          const int e = lr0 + r;
          const int grow = base + e;
          if (grow < nrows) {
            const float h = acc[nt][r] + (USEP ? pv[nt][r] : bb);
            const float o = silu(h * sc + sh);
            if (MODE == 1) {
              unsafeAtomicAdd(&sums_out[(size_t)coltile[e] * 64 + c], o);
            } else {
              __builtin_nontemporal_store(o, &out[(size_t)grow * 64 + c]);
            }
          }
        }
        if (MODE == 1 && nt == 0 && m == 0) {
#pragma unroll
          for (int r = 0; r < 4; ++r) {
            const int e = lr0 + r;
            if (base + e < nrows) unsafeAtomicAdd(&cnt_out[coltile[e]], 1.0f);
          }
        }
      }
    }
  }

  if (MODE == 0 || MODE == 2) {
    __syncthreads();
    if (tid < 128) {
      const int c = tid & 63;
      if (tid < 64) {
        unsafeAtomicAdd(&ssum[c], wsum[0][c] + wsum[1][c] + wsum[2][c] + wsum[3][c]);
      } else {
        unsafeAtomicAdd(&ssq[c], wsq[0][c] + wsq[1][c] + wsq[2][c] + wsq[3][c]);
      }
    }
  }
}

__global__ void finalize_stats(const float* __restrict__ ss, const float* __restrict__ sq,
                               const float* __restrict__ g, const float* __restrict__ be,
                               float* __restrict__ scsh, float invn) {
  const int c = threadIdx.x;  // 64 threads
  const float mu  = ss[c] * invn;
  const float var = sq[c] * invn - mu * mu;
  const float rs  = rsqrtf(fmaxf(var, 0.0f) + EPS);
  const float s   = g[c] * rs;
  scsh[c]      = s;
  scsh[64 + c] = be[c] - mu * s;
}

extern "C" void kernel_launch(void* const* d_in, const int* in_sizes, int n_in,
                              void* d_out, int out_size, void* d_ws, size_t ws_size,
                              hipStream_t stream) {
  const int N = in_sizes[0] / 64;
  const int E = in_sizes[1] / 64;
  const float* x   = (const float*)d_in[0];
  const float* ea  = (const float*)d_in[1];
  // d_in[2] = u (unused by reference)
  const float* W1  = (const float*)d_in[3];
  const float* b1  = (const float*)d_in[4];
  const float* g1  = (const float*)d_in[5];
  const float* be1 = (const float*)d_in[6];
  const float* W2  = (const float*)d_in[7];
  const float* b2  = (const float*)d_in[8];
  const float* g2  = (const float*)d_in[9];
  const float* be2 = (const float*)d_in[10];
  const int* ei   = (const int*)d_in[11];  // [2,E] int32
  const int* row  = ei;
  const int* colv = ei + E;
  // d_in[12] = batch (unused by reference)

  float* sums  = (float*)d_ws;          // N*64
  float* cnt   = sums + (size_t)N * 64; // N
  float* statE = cnt + N;               // 128 (sum | sumsq)
  float* statN = statE + 128;           // 128
  float* scsh1 = statN + 128;           // 128 (scale | shift)
  float* scsh2 = scsh1 + 128;           // 128
  ushort* Pbf  = (ushort*)(scsh2 + 128); // N*64 bf16 (P1, later P2)

  const size_t baseFloats = (size_t)N * 65 + 512;
  const size_t needP = (baseFloats + (size_t)N * 32) * sizeof(float);
  const bool useP = (ws_size >= needP);

  // Only the 512-float stats/scsh region needs a serial zero; sums/cnt are
  // zeroed inside pass0 (grid-stride, overlapped with its GEMM work).
  hipMemsetAsync(statE, 0, 512 * sizeof(float), stream);

  const int ntE = (E + 63) / 64;
  const int ntN = (N + 63) / 64;
  const int gE  = ntE < 2048 ? ntE : 2048;
  const int gN  = ntN < 2048 ? ntN : 2048;
  const int zn  = N * 65;  // sums + cnt (contiguous), in floats

  if (useP) {
    precompute_P<<<dim3(gN), dim3(256), 0, stream>>>(x, W1, b1, Pbf, N, ntN);
    fused_gemm<0, 1><<<dim3(gE), dim3(256), 0, stream>>>(
        x, ea, nullptr, nullptr, row, nullptr, W1, b1, nullptr, Pbf,
        statE, statE + 64, nullptr, nullptr, nullptr, sums, zn, E, ntE);
    finalize_stats<<<dim3(1), dim3(64), 0, stream>>>(statE, statE + 64, g1, be1, scsh1,
                                                     1.0f / (float)E);
    fused_gemm<1, 1><<<dim3(gE), dim3(256), 0, stream>>>(
        x, ea, nullptr, nullptr, row, colv, W1, b1, scsh1, Pbf,
        nullptr, nullptr, sums, cnt, nullptr, nullptr, 0, E, ntE);
    precompute_P<<<dim3(gN), dim3(256), 0, stream>>>(x, W2, b2, Pbf, N, ntN);
    fused_gemm<2, 1><<<dim3(gN), dim3(256), 0, stream>>>(
        x, nullptr, sums, cnt, nullptr, nullptr, W2, b2, nullptr, Pbf,
        statN, statN + 64, nullptr, nullptr, nullptr, nullptr, 0, N, ntN);
    finalize_stats<<<dim3(1), dim3(64), 0, stream>>>(statN, statN + 64, g2, be2, scsh2,
                                                     1.0f / (float)N);
    fused_gemm<3, 1><<<dim3(gN), dim3(256), 0, stream>>>(
        x, nullptr, sums, cnt, nullptr, nullptr, W2, b2, scsh2, Pbf,
        nullptr, nullptr, nullptr, nullptr, (float*)d_out, nullptr, 0, N, ntN);
  } else {
    fused_gemm<0, 0><<<dim3(gE), dim3(256), 0, stream>>>(
        x, ea, nullptr, nullptr, row, nullptr, W1, b1, nullptr, nullptr,
        statE, statE + 64, nullptr, nullptr, nullptr, sums, zn, E, ntE);
    finalize_stats<<<dim3(1), dim3(64), 0, stream>>>(statE, statE + 64, g1, be1, scsh1,
                                                     1.0f / (float)E);
    fused_gemm<1, 0><<<dim3(gE), dim3(256), 0, stream>>>(
        x, ea, nullptr, nullptr, row, colv, W1, b1, scsh1, nullptr,
        nullptr, nullptr, sums, cnt, nullptr, nullptr, 0, E, ntE);
    fused_gemm<2, 0><<<dim3(gN), dim3(256), 0, stream>>>(
        x, nullptr, sums, cnt, nullptr, nullptr, W2, b2, nullptr, nullptr,
        statN, statN + 64, nullptr, nullptr, nullptr, nullptr, 0, N, ntN);
    finalize_stats<<<dim3(1), dim3(64), 0, stream>>>(statN, statN + 64, g2, be2, scsh2,
                                                     1.0f / (float)N);
    fused_gemm<3, 0><<<dim3(gN), dim3(256), 0, stream>>>(
        x, nullptr, sums, cnt, nullptr, nullptr, W2, b2, scsh2, nullptr,
        nullptr, nullptr, nullptr, nullptr, (float*)d_out, nullptr, 0, N, ntN);
  }
}